// Round 2
// baseline (105002.930 us; speedup 1.0000x reference)
//
#include <hip/hip_runtime.h>
#include <math.h>

#define T_LEN 512
#define B_SZ  32
#define I_DIM 512
#define H_DIM 1024
#define NBLK  256

// ---------------------------------------------------------------------------
// bias_combine: bias4[4096] = per-gate folded biases
// ---------------------------------------------------------------------------
__global__ void bias_combine(const float* __restrict__ b_ii, const float* __restrict__ b_hi,
                             const float* __restrict__ b_ci, const float* __restrict__ b_if,
                             const float* __restrict__ b_hf, const float* __restrict__ b_cf,
                             const float* __restrict__ b_ic, const float* __restrict__ b_hc,
                             const float* __restrict__ b_io, const float* __restrict__ b_ho,
                             const float* __restrict__ b_cyo, float* __restrict__ bias4) {
    int r = blockIdx.x * 256 + threadIdx.x;
    if (r < H_DIM) {
        bias4[r]            = b_ii[r] + b_hi[r] + b_ci[r];
        bias4[1024 + r]     = b_if[r] + b_hf[r] + b_cf[r];
        bias4[2048 + r]     = b_ic[r] + b_hc[r];
        bias4[3072 + r]     = b_io[r] + b_ho[r] + b_cyo[r];
    }
}

// ---------------------------------------------------------------------------
// pregemm: G[m][n] = sum_k X[m][k]*Wg[nloc][k] + bias4[n]; M=Tc*32,K=512,N=4096
// ---------------------------------------------------------------------------
#define BM 128
#define BN 128
#define BK 16
__global__ __launch_bounds__(256) void pregemm(const float* __restrict__ A,
                                               const float* __restrict__ w0,
                                               const float* __restrict__ w1,
                                               const float* __restrict__ w2,
                                               const float* __restrict__ w3,
                                               const float* __restrict__ bias4,
                                               float* __restrict__ C) {
    __shared__ float As[BK][BM + 4];
    __shared__ float Bs[BK][BN + 4];
    int tid = threadIdx.x;
    int n0 = blockIdx.y * BN;
    const float* W = (n0 < 1024) ? w0 : (n0 < 2048) ? w1 : (n0 < 3072) ? w2 : w3;
    int nloc = n0 & 1023;

    int lr = tid >> 2;
    int lk = (tid & 3) << 2;
    const float* Arow = A + (size_t)(blockIdx.x * BM + lr) * I_DIM + lk;
    const float* Brow = W + (size_t)(nloc + lr) * I_DIM + lk;

    float acc[8][8];
#pragma unroll
    for (int i = 0; i < 8; ++i)
#pragma unroll
        for (int j = 0; j < 8; ++j) acc[i][j] = 0.f;

    int mth = (tid >> 4) << 3;
    int nth = (tid & 15) << 3;

    for (int kt = 0; kt < I_DIM; kt += BK) {
        float4 a0 = *(const float4*)(Arow + kt);
        float4 a1 = *(const float4*)(Arow + 64 * I_DIM + kt);
        float4 b0 = *(const float4*)(Brow + kt);
        float4 b1 = *(const float4*)(Brow + 64 * I_DIM + kt);
        __syncthreads();
        As[lk + 0][lr] = a0.x; As[lk + 1][lr] = a0.y; As[lk + 2][lr] = a0.z; As[lk + 3][lr] = a0.w;
        As[lk + 0][lr + 64] = a1.x; As[lk + 1][lr + 64] = a1.y; As[lk + 2][lr + 64] = a1.z; As[lk + 3][lr + 64] = a1.w;
        Bs[lk + 0][lr] = b0.x; Bs[lk + 1][lr] = b0.y; Bs[lk + 2][lr] = b0.z; Bs[lk + 3][lr] = b0.w;
        Bs[lk + 0][lr + 64] = b1.x; Bs[lk + 1][lr + 64] = b1.y; Bs[lk + 2][lr + 64] = b1.z; Bs[lk + 3][lr + 64] = b1.w;
        __syncthreads();
#pragma unroll
        for (int j = 0; j < BK; ++j) {
            float am[8], bn[8];
            *(float4*)&am[0] = *(const float4*)&As[j][mth];
            *(float4*)&am[4] = *(const float4*)&As[j][mth + 4];
            *(float4*)&bn[0] = *(const float4*)&Bs[j][nth];
            *(float4*)&bn[4] = *(const float4*)&Bs[j][nth + 4];
#pragma unroll
            for (int ii = 0; ii < 8; ++ii)
#pragma unroll
                for (int jj = 0; jj < 8; ++jj) acc[ii][jj] += am[ii] * bn[jj];
        }
    }

    float bb[8];
    *(float4*)&bb[0] = *(const float4*)&bias4[n0 + nth];
    *(float4*)&bb[4] = *(const float4*)&bias4[n0 + nth + 4];
    size_t mbase = (size_t)(blockIdx.x * BM + mth);
#pragma unroll
    for (int ii = 0; ii < 8; ++ii) {
        float* crow = C + (mbase + ii) * 4096 + n0 + nth;
        float4 v0, v1;
        v0.x = acc[ii][0] + bb[0]; v0.y = acc[ii][1] + bb[1];
        v0.z = acc[ii][2] + bb[2]; v0.w = acc[ii][3] + bb[3];
        v1.x = acc[ii][4] + bb[4]; v1.y = acc[ii][5] + bb[5];
        v1.z = acc[ii][6] + bb[6]; v1.w = acc[ii][7] + bb[7];
        *(float4*)crow = v0;
        *(float4*)(crow + 4) = v1;
    }
}

// ---------------------------------------------------------------------------
// Persistent cooperative scan kernel.
// 256 blocks x 512 threads (8 waves), 1 block/CU. Block owns rows r0..r0+3.
// All 7 weight-matrix row-slices (112 KB) live in LDS for the whole scan.
// Per step: phaseA (i,f,g -> cy; po=xo+h@w_ho) | grid barrier |
//           phaseB (o = sig(po + cy@w_cyo); hy) | grid barrier |
// ---------------------------------------------------------------------------
#define SMEM_FLOATS (24576 + 4096 + 4224 + 4224 + 768 + 128 + 128)
#define SMEM_BYTES  (SMEM_FLOATS * 4)

__device__ __forceinline__ float dot4(float4 w, float4 x) {
    return w.x * x.x + w.y * x.y + w.z * x.z + w.w * x.w;
}

__global__ __launch_bounds__(512, 2) void lstm_scan(
    const float* __restrict__ G,
    const float* __restrict__ h0,
    const float* __restrict__ c0,
    const float* __restrict__ w_hi, const float* __restrict__ w_ci,
    const float* __restrict__ w_hf, const float* __restrict__ w_cf,
    const float* __restrict__ w_hc, const float* __restrict__ w_ho,
    const float* __restrict__ w_cyo,
    float* __restrict__ out,
    float* __restrict__ cpp,
    unsigned* __restrict__ ctr,
    int t0, int Tc)
{
    extern __shared__ float smem[];
    float* wA   = smem;               // [6][4][1024]
    float* wB   = wA + 24576;         // [4][1024]
    float* hs   = wB + 4096;          // [32][132]
    float* cs   = hs + 4224;          // [32][132]
    float* red6 = cs + 4224;          // [4][6][32]
    float* redB = red6 + 768;         // [4][32]
    float* po   = redB + 128;         // [4][32]

    int tid = threadIdx.x;
    int blk = blockIdx.x;
    int r0 = blk * 4;

    int wv = tid >> 6;            // 0..7
    int lane = tid & 63;
    int rw = wv & 3;              // row within block slice
    int kg = wv >> 2;             // k half
    int half = lane >> 5;         // k quarter within half
    int b = lane & 31;            // batch
    int r = r0 + rw;
    int klbase = kg * 64 + half * 32;

    int bb = tid >> 4;            // staging row 0..31
    int slot = tid & 15;          // 0..15
    int kk = slot * 4;

    // ---- load weight slices into LDS once ----
    {
        const float* srcs[7] = {w_hi, w_ci, w_hf, w_cf, w_hc, w_ho, w_cyo};
#pragma unroll
        for (int m = 0; m < 7; ++m) {
            const float4* s = (const float4*)(srcs[m] + (size_t)r0 * H_DIM);
            float4* d = (float4*)(m < 6 ? (wA + m * 4096) : wB);
            d[tid] = s[tid];
            d[tid + 512] = s[tid + 512];
        }
    }
    __syncthreads();

    unsigned target = 0;

    for (int tt = 0; tt < Tc; ++tt) {
        int t = t0 + tt;
        const float* h_in = (t == 0) ? h0 : out + (size_t)(t - 1) * (B_SZ * H_DIM);
        const float* c_in = (t == 0) ? c0 : cpp + (size_t)(t & 1) * (B_SZ * H_DIM);
        float* c_out = cpp + (size_t)((t + 1) & 1) * (B_SZ * H_DIM);
        const float* Gt = G + (size_t)tt * (B_SZ * 4096);

        // ================= phase A =================
        float acc0 = 0.f, acc1 = 0.f, acc2 = 0.f, acc3 = 0.f, acc4 = 0.f, acc5 = 0.f;
        for (int cc = 0; cc < 8; ++cc) {
            int k0 = cc * 128;
            __syncthreads();
            {
                const float* hrow = h_in + (size_t)bb * H_DIM + k0;
                const float* crow = c_in + (size_t)bb * H_DIM + k0;
                *(float4*)&hs[bb * 132 + kk]      = *(const float4*)(hrow + kk);
                *(float4*)&hs[bb * 132 + kk + 64] = *(const float4*)(hrow + kk + 64);
                *(float4*)&cs[bb * 132 + kk]      = *(const float4*)(crow + kk);
                *(float4*)&cs[bb * 132 + kk + 64] = *(const float4*)(crow + kk + 64);
            }
            __syncthreads();
#pragma unroll
            for (int j = 0; j < 8; ++j) {
                int kl = klbase + j * 4;
                float4 h4 = *(const float4*)&hs[b * 132 + kl];
                float4 c4 = *(const float4*)&cs[b * 132 + kl];
                int kw = k0 + kl;
                acc0 += dot4(*(const float4*)&wA[(0 * 4 + rw) * 1024 + kw], h4);
                acc1 += dot4(*(const float4*)&wA[(1 * 4 + rw) * 1024 + kw], c4);
                acc2 += dot4(*(const float4*)&wA[(2 * 4 + rw) * 1024 + kw], h4);
                acc3 += dot4(*(const float4*)&wA[(3 * 4 + rw) * 1024 + kw], c4);
                acc4 += dot4(*(const float4*)&wA[(4 * 4 + rw) * 1024 + kw], h4);
                acc5 += dot4(*(const float4*)&wA[(5 * 4 + rw) * 1024 + kw], h4);
            }
        }
        acc0 += __shfl_xor(acc0, 32);
        acc1 += __shfl_xor(acc1, 32);
        acc2 += __shfl_xor(acc2, 32);
        acc3 += __shfl_xor(acc3, 32);
        acc4 += __shfl_xor(acc4, 32);
        acc5 += __shfl_xor(acc5, 32);
        if (kg == 1 && half == 0) {
            red6[(rw * 6 + 0) * 32 + b] = acc0;
            red6[(rw * 6 + 1) * 32 + b] = acc1;
            red6[(rw * 6 + 2) * 32 + b] = acc2;
            red6[(rw * 6 + 3) * 32 + b] = acc3;
            red6[(rw * 6 + 4) * 32 + b] = acc4;
            red6[(rw * 6 + 5) * 32 + b] = acc5;
        }
        __syncthreads();
        if (kg == 0 && half == 0) {
            acc0 += red6[(rw * 6 + 0) * 32 + b];
            acc1 += red6[(rw * 6 + 1) * 32 + b];
            acc2 += red6[(rw * 6 + 2) * 32 + b];
            acc3 += red6[(rw * 6 + 3) * 32 + b];
            acc4 += red6[(rw * 6 + 4) * 32 + b];
            acc5 += red6[(rw * 6 + 5) * 32 + b];
            const float* Gb = Gt + (size_t)b * 4096;
            float xi = Gb[r];
            float xf = Gb[1024 + r];
            float xg = Gb[2048 + r];
            float xo = Gb[3072 + r];
            float iv = 1.f / (1.f + expf(-(xi + acc0 + acc1)));
            float fv = 1.f / (1.f + expf(-(xf + acc2 + acc3)));
            float gv = tanhf(xg + acc4);
            int idx = b * H_DIM + r;
            float cy = fv * c_in[idx] + iv * gv;
            c_out[idx] = cy;
            po[rw * 32 + b] = xo + acc5;
        }

        // ---- grid barrier: cy visible everywhere ----
        target += NBLK;
        __threadfence();
        __syncthreads();
        if (tid == 0) {
            __hip_atomic_fetch_add(ctr, 1u, __ATOMIC_RELEASE, __HIP_MEMORY_SCOPE_AGENT);
            while (__hip_atomic_load(ctr, __ATOMIC_RELAXED, __HIP_MEMORY_SCOPE_AGENT) < target)
                __builtin_amdgcn_s_sleep(2);
        }
        __syncthreads();
        __threadfence();

        // ================= phase B =================
        float accB = 0.f;
        for (int cc = 0; cc < 8; ++cc) {
            int k0 = cc * 128;
            __syncthreads();
            {
                const float* cyrow = c_out + (size_t)bb * H_DIM + k0;
                *(float4*)&hs[bb * 132 + kk]      = *(const float4*)(cyrow + kk);
                *(float4*)&hs[bb * 132 + kk + 64] = *(const float4*)(cyrow + kk + 64);
            }
            __syncthreads();
#pragma unroll
            for (int j = 0; j < 8; ++j) {
                int kl = klbase + j * 4;
                float4 cy4 = *(const float4*)&hs[b * 132 + kl];
                accB += dot4(*(const float4*)&wB[rw * 1024 + k0 + kl], cy4);
            }
        }
        accB += __shfl_xor(accB, 32);
        if (kg == 1 && half == 0) redB[rw * 32 + b] = accB;
        __syncthreads();
        if (kg == 0 && half == 0) {
            accB += redB[rw * 32 + b];
            int idx = b * H_DIM + r;
            float cyv = c_out[idx];
            float o = 1.f / (1.f + expf(-(po[rw * 32 + b] + accB)));
            out[(size_t)t * (B_SZ * H_DIM) + idx] = o * tanhf(cyv);
        }

        // ---- grid barrier: h(t) visible everywhere ----
        target += NBLK;
        __threadfence();
        __syncthreads();
        if (tid == 0) {
            __hip_atomic_fetch_add(ctr, 1u, __ATOMIC_RELEASE, __HIP_MEMORY_SCOPE_AGENT);
            while (__hip_atomic_load(ctr, __ATOMIC_RELAXED, __HIP_MEMORY_SCOPE_AGENT) < target)
                __builtin_amdgcn_s_sleep(2);
        }
        __syncthreads();
        __threadfence();
    }
}

// ---------------------------------------------------------------------------
extern "C" void kernel_launch(void* const* d_in, const int* in_sizes, int n_in,
                              void* d_out, int out_size, void* d_ws, size_t ws_size,
                              hipStream_t stream) {
    const float* X     = (const float*)d_in[0];
    const float* h0    = (const float*)d_in[1];
    const float* c0    = (const float*)d_in[2];
    const float* w_ii  = (const float*)d_in[3];
    const float* w_hi  = (const float*)d_in[4];
    const float* w_ci  = (const float*)d_in[5];
    const float* w_if  = (const float*)d_in[6];
    const float* w_hf  = (const float*)d_in[7];
    const float* w_cf  = (const float*)d_in[8];
    const float* w_ic  = (const float*)d_in[9];
    const float* w_hc  = (const float*)d_in[10];
    const float* w_io  = (const float*)d_in[11];
    const float* w_ho  = (const float*)d_in[12];
    const float* w_cyo = (const float*)d_in[13];
    const float* b_ii  = (const float*)d_in[14];
    const float* b_hi  = (const float*)d_in[15];
    const float* b_ci  = (const float*)d_in[16];
    const float* b_if  = (const float*)d_in[17];
    const float* b_hf  = (const float*)d_in[18];
    const float* b_cf  = (const float*)d_in[19];
    const float* b_ic  = (const float*)d_in[20];
    const float* b_hc  = (const float*)d_in[21];
    const float* b_io  = (const float*)d_in[22];
    const float* b_ho  = (const float*)d_in[23];
    const float* b_cyo = (const float*)d_in[24];
    float* out = (float*)d_out;

    // allow >64KB dynamic LDS for the persistent kernel (idempotent)
    (void)hipFuncSetAttribute((const void*)lstm_scan,
                              hipFuncAttributeMaxDynamicSharedMemorySize, SMEM_BYTES);

    // workspace carve
    const size_t extra_floats = 4096 + 2 * (size_t)B_SZ * H_DIM;
    int Tc = 512;
    while (Tc > 8 && (size_t)Tc * B_SZ * 4096 * 4 + extra_floats * 4 + 256 > ws_size) Tc >>= 1;

    float* G     = (float*)d_ws;
    float* bias4 = G + (size_t)Tc * B_SZ * 4096;
    float* cpp   = bias4 + 4096;
    unsigned* ctr = (unsigned*)(cpp + 2 * (size_t)B_SZ * H_DIM);

    bias_combine<<<4, 256, 0, stream>>>(b_ii, b_hi, b_ci, b_if, b_hf, b_cf,
                                        b_ic, b_hc, b_io, b_ho, b_cyo, bias4);

    for (int t0 = 0; t0 < T_LEN; t0 += Tc) {
        pregemm<<<dim3(Tc * 32 / BM, 4096 / BN), 256, 0, stream>>>(
            X + (size_t)t0 * B_SZ * I_DIM, w_ii, w_if, w_ic, w_io, bias4, G);
        hipMemsetAsync(ctr, 0, 64, stream);

        const float* Gp = G;
        float* cppp = cpp;
        unsigned* ctrp = ctr;
        int t0v = t0, Tcv = Tc;
        void* args[] = {
            (void*)&Gp, (void*)&h0, (void*)&c0,
            (void*)&w_hi, (void*)&w_ci, (void*)&w_hf, (void*)&w_cf,
            (void*)&w_hc, (void*)&w_ho, (void*)&w_cyo,
            (void*)&out, (void*)&cppp, (void*)&ctrp,
            (void*)&t0v, (void*)&Tcv
        };
        hipLaunchCooperativeKernel((const void*)lstm_scan, dim3(NBLK), dim3(512),
                                   args, SMEM_BYTES, stream);
    }
}

// Round 3
// 29803.564 us; speedup vs baseline: 3.5232x; 3.5232x over previous
//
#include <hip/hip_runtime.h>
#include <math.h>

#define T_LEN 512
#define B_SZ  32
#define I_DIM 512
#define H_DIM 1024
#define NBLK  256
#define HS    (B_SZ * H_DIM)   // 32768 floats per state snapshot

// ---------------------------------------------------------------------------
// bias_combine
// ---------------------------------------------------------------------------
__global__ void bias_combine(const float* __restrict__ b_ii, const float* __restrict__ b_hi,
                             const float* __restrict__ b_ci, const float* __restrict__ b_if,
                             const float* __restrict__ b_hf, const float* __restrict__ b_cf,
                             const float* __restrict__ b_ic, const float* __restrict__ b_hc,
                             const float* __restrict__ b_io, const float* __restrict__ b_ho,
                             const float* __restrict__ b_cyo, float* __restrict__ bias4) {
    int r = blockIdx.x * 256 + threadIdx.x;
    if (r < H_DIM) {
        bias4[r]        = b_ii[r] + b_hi[r] + b_ci[r];
        bias4[1024 + r] = b_if[r] + b_hf[r] + b_cf[r];
        bias4[2048 + r] = b_ic[r] + b_hc[r];
        bias4[3072 + r] = b_io[r] + b_ho[r] + b_cyo[r];
    }
}

// ---------------------------------------------------------------------------
// pregemm (unchanged from R1 — passed)
// ---------------------------------------------------------------------------
#define BM 128
#define BN 128
#define BK 16
__global__ __launch_bounds__(256) void pregemm(const float* __restrict__ A,
                                               const float* __restrict__ w0,
                                               const float* __restrict__ w1,
                                               const float* __restrict__ w2,
                                               const float* __restrict__ w3,
                                               const float* __restrict__ bias4,
                                               float* __restrict__ C) {
    __shared__ float As[BK][BM + 4];
    __shared__ float Bs[BK][BN + 4];
    int tid = threadIdx.x;
    int n0 = blockIdx.y * BN;
    const float* W = (n0 < 1024) ? w0 : (n0 < 2048) ? w1 : (n0 < 3072) ? w2 : w3;
    int nloc = n0 & 1023;

    int lr = tid >> 2;
    int lk = (tid & 3) << 2;
    const float* Arow = A + (size_t)(blockIdx.x * BM + lr) * I_DIM + lk;
    const float* Brow = W + (size_t)(nloc + lr) * I_DIM + lk;

    float acc[8][8];
#pragma unroll
    for (int i = 0; i < 8; ++i)
#pragma unroll
        for (int j = 0; j < 8; ++j) acc[i][j] = 0.f;

    int mth = (tid >> 4) << 3;
    int nth = (tid & 15) << 3;

    for (int kt = 0; kt < I_DIM; kt += BK) {
        float4 a0 = *(const float4*)(Arow + kt);
        float4 a1 = *(const float4*)(Arow + 64 * I_DIM + kt);
        float4 b0 = *(const float4*)(Brow + kt);
        float4 b1 = *(const float4*)(Brow + 64 * I_DIM + kt);
        __syncthreads();
        As[lk + 0][lr] = a0.x; As[lk + 1][lr] = a0.y; As[lk + 2][lr] = a0.z; As[lk + 3][lr] = a0.w;
        As[lk + 0][lr + 64] = a1.x; As[lk + 1][lr + 64] = a1.y; As[lk + 2][lr + 64] = a1.z; As[lk + 3][lr + 64] = a1.w;
        Bs[lk + 0][lr] = b0.x; Bs[lk + 1][lr] = b0.y; Bs[lk + 2][lr] = b0.z; Bs[lk + 3][lr] = b0.w;
        Bs[lk + 0][lr + 64] = b1.x; Bs[lk + 1][lr + 64] = b1.y; Bs[lk + 2][lr + 64] = b1.z; Bs[lk + 3][lr + 64] = b1.w;
        __syncthreads();
#pragma unroll
        for (int j = 0; j < BK; ++j) {
            float am[8], bn[8];
            *(float4*)&am[0] = *(const float4*)&As[j][mth];
            *(float4*)&am[4] = *(const float4*)&As[j][mth + 4];
            *(float4*)&bn[0] = *(const float4*)&Bs[j][nth];
            *(float4*)&bn[4] = *(const float4*)&Bs[j][nth + 4];
#pragma unroll
            for (int ii = 0; ii < 8; ++ii)
#pragma unroll
                for (int jj = 0; jj < 8; ++jj) acc[ii][jj] += am[ii] * bn[jj];
        }
    }

    float bb[8];
    *(float4*)&bb[0] = *(const float4*)&bias4[n0 + nth];
    *(float4*)&bb[4] = *(const float4*)&bias4[n0 + nth + 4];
    size_t mbase = (size_t)(blockIdx.x * BM + mth);
#pragma unroll
    for (int ii = 0; ii < 8; ++ii) {
        float* crow = C + (mbase + ii) * 4096 + n0 + nth;
        float4 v0, v1;
        v0.x = acc[ii][0] + bb[0]; v0.y = acc[ii][1] + bb[1];
        v0.z = acc[ii][2] + bb[2]; v0.w = acc[ii][3] + bb[3];
        v1.x = acc[ii][4] + bb[4]; v1.y = acc[ii][5] + bb[5];
        v1.z = acc[ii][6] + bb[6]; v1.w = acc[ii][7] + bb[7];
        *(float4*)crow = v0;
        *(float4*)(crow + 4) = v1;
    }
}

// ---------------------------------------------------------------------------
// helpers
// ---------------------------------------------------------------------------
__device__ __forceinline__ float sigm(float x) { return 1.f / (1.f + __expf(-x)); }
__device__ __forceinline__ float tanh_fast(float x) { return 2.f / (1.f + __expf(-2.f * x)) - 1.f; }

__device__ __forceinline__ void agent_store(float* p, float v) {
    __hip_atomic_store(p, v, __ATOMIC_RELAXED, __HIP_MEMORY_SCOPE_AGENT);
}

// two-level arrival barrier (thread 0 only); no cache-flush fences.
__device__ __forceinline__ void arrive_wait(unsigned* grp, unsigned* master,
                                            int grpid, unsigned bidx) {
    unsigned old = __hip_atomic_fetch_add(&grp[grpid * 16], 1u,
                                          __ATOMIC_RELAXED, __HIP_MEMORY_SCOPE_AGENT);
    if (old == bidx * 32u + 31u)
        __hip_atomic_fetch_add(master, 1u, __ATOMIC_RELAXED, __HIP_MEMORY_SCOPE_AGENT);
    while (__hip_atomic_load(master, __ATOMIC_RELAXED, __HIP_MEMORY_SCOPE_AGENT)
           < (bidx + 1u) * 8u)
        __builtin_amdgcn_s_sleep(1);
}

// ---------------------------------------------------------------------------
// Persistent cooperative scan. 256 blocks x 512 thr (8 waves). Block owns
// physical rows r0..r0+3 (=> 24 gate-rows in phaseA, 4 in phaseB).
// Weights stream from global (L2-resident: 112 KB/block). Wave wv owns
// k-slice [wv*128, wv*128+128). Lane: half = lane>>5 owns a gate-row group
// arranged so the state operand (h or c) is uniform per slot; b = lane&31.
// 12 accumulators/lane. Cross-wave k-reduction through LDS.
// ---------------------------------------------------------------------------
__global__ __launch_bounds__(512) void lstm_scan(
    const float* __restrict__ G,
    const float* __restrict__ h0,
    const float* __restrict__ c_init,
    const float* __restrict__ w_hi, const float* __restrict__ w_ci,
    const float* __restrict__ w_hf, const float* __restrict__ w_cf,
    const float* __restrict__ w_hc, const float* __restrict__ w_ho,
    const float* __restrict__ w_cyo,
    float* __restrict__ out,
    float* __restrict__ c_hist,
    unsigned* __restrict__ grp_ctr,
    unsigned* __restrict__ master,
    int t0, int Tc)
{
    __shared__ float redA[8 * 24 * 32];   // 24 KB: k-split partials
    __shared__ float po_lds[128];
    __shared__ float cy_lds[128];

    int tid = threadIdx.x;
    int blk = blockIdx.x;
    int r0 = blk * 4;
    int grpid = blk & 7;

    int wv = tid >> 6;            // 0..7 : k-split
    int lane = tid & 63;
    int half = lane >> 5;         // gate-row group
    int b = lane & 31;            // batch
    int kbase = wv * 128;

    // slot gates: slot0/2 consume h, slot1 consumes c — uniform across halves.
    int gs0 = half ? 2 : 0;       // w_hf : w_hi   (h)
    int gs1 = half ? 3 : 1;       // w_cf : w_ci   (c)
    int gs2 = half ? 5 : 4;       // w_ho : w_hc   (h)
    const float* wm[6] = {w_hi, w_ci, w_hf, w_cf, w_hc, w_ho};

    // per-lane weight pointers, kbase folded in (step-invariant)
    const float* wpk[12];
#pragma unroll
    for (int q = 0; q < 4; ++q) {
        wpk[q]     = wm[gs0] + (size_t)(r0 + q) * H_DIM + kbase;
        wpk[4 + q] = wm[gs1] + (size_t)(r0 + q) * H_DIM + kbase;
        wpk[8 + q] = wm[gs2] + (size_t)(r0 + q) * H_DIM + kbase;
    }
    const float* wBk0 = w_cyo + (size_t)(r0 + half * 2 + 0) * H_DIM + kbase;
    const float* wBk1 = w_cyo + (size_t)(r0 + half * 2 + 1) * H_DIM + kbase;

    // finisher mapping (threads 0..127)
    int frw = (tid >> 5) & 3;
    int fb = tid & 31;
    int fr = r0 + frw;

    unsigned bidx = 0;

    for (int tt = 0; tt < Tc; ++tt) {
        int t = t0 + tt;
        const float* hp = (t == 0) ? h0 : out + (size_t)(t - 1) * HS;
        const float* cp = (tt == 0) ? c_init : c_hist + (size_t)tt * HS;
        float* cw = c_hist + (size_t)(tt + 1) * HS;
        const float* Gt = G + (size_t)tt * (B_SZ * 4096);

        // ---------------- phase A main: 24 gate-row partial dots ----------------
        const float* hb = hp + (size_t)b * H_DIM + kbase;
        const float* cb = cp + (size_t)b * H_DIM + kbase;
        float acc[12];
#pragma unroll
        for (int j = 0; j < 12; ++j) acc[j] = 0.f;

#pragma unroll 2
        for (int it = 0; it < 32; ++it) {
            int k = it * 4;
            float4 h4 = *(const float4*)(hb + k);
            float4 c4 = *(const float4*)(cb + k);
#pragma unroll
            for (int q = 0; q < 4; ++q) {
                float4 w4 = *(const float4*)(wpk[q] + k);
                acc[q] += w4.x * h4.x + w4.y * h4.y + w4.z * h4.z + w4.w * h4.w;
            }
#pragma unroll
            for (int q = 0; q < 4; ++q) {
                float4 w4 = *(const float4*)(wpk[4 + q] + k);
                acc[4 + q] += w4.x * c4.x + w4.y * c4.y + w4.z * c4.z + w4.w * c4.w;
            }
#pragma unroll
            for (int q = 0; q < 4; ++q) {
                float4 w4 = *(const float4*)(wpk[8 + q] + k);
                acc[8 + q] += w4.x * h4.x + w4.y * h4.y + w4.z * h4.z + w4.w * h4.w;
            }
        }
        // write partials: gate-row = g*4 + q
#pragma unroll
        for (int q = 0; q < 4; ++q) {
            redA[wv * 768 + (gs0 * 4 + q) * 32 + b] = acc[q];
            redA[wv * 768 + (gs1 * 4 + q) * 32 + b] = acc[4 + q];
            redA[wv * 768 + (gs2 * 4 + q) * 32 + b] = acc[8 + q];
        }
        __syncthreads();

        // ---------------- phase A finisher (threads 0..127) ----------------
        if (tid < 128) {
            float s[6];
#pragma unroll
            for (int g = 0; g < 6; ++g) {
                float v = 0.f;
#pragma unroll
                for (int k8 = 0; k8 < 8; ++k8)
                    v += redA[k8 * 768 + (g * 4 + frw) * 32 + fb];
                s[g] = v;
            }
            const float* Gb = Gt + (size_t)fb * 4096;
            float xi = Gb[fr];
            float xf = Gb[1024 + fr];
            float xg = Gb[2048 + fr];
            float xo = Gb[3072 + fr];
            float iv = sigm(xi + s[0] + s[1]);
            float fv = sigm(xf + s[2] + s[3]);
            float gv = tanh_fast(xg + s[4]);
            float cold = cp[(size_t)fb * H_DIM + fr];
            float cy = fv * cold + iv * gv;
            agent_store(&cw[(size_t)fb * H_DIM + fr], cy);
            po_lds[frw * 32 + fb] = xo + s[5];
            cy_lds[frw * 32 + fb] = cy;
        }
        __syncthreads();              // drains the agent stores (vmcnt) too

        // ---------------- barrier: cy globally visible ----------------
        if (tid == 0) arrive_wait(grp_ctr, master, grpid, bidx);
        bidx++;
        __builtin_amdgcn_fence(__ATOMIC_ACQUIRE, "workgroup");
        __syncthreads();

        // ---------------- phase B main: o-gate peephole dot ----------------
        const float* cyb = cw + (size_t)b * H_DIM + kbase;
        float a0 = 0.f, a1 = 0.f;
#pragma unroll 2
        for (int it = 0; it < 32; ++it) {
            int k = it * 4;
            float4 cy4 = *(const float4*)(cyb + k);
            float4 w0 = *(const float4*)(wBk0 + k);
            float4 w1 = *(const float4*)(wBk1 + k);
            a0 += w0.x * cy4.x + w0.y * cy4.y + w0.z * cy4.z + w0.w * cy4.w;
            a1 += w1.x * cy4.x + w1.y * cy4.y + w1.z * cy4.z + w1.w * cy4.w;
        }
        redA[wv * 128 + (half * 2 + 0) * 32 + b] = a0;
        redA[wv * 128 + (half * 2 + 1) * 32 + b] = a1;
        __syncthreads();

        // ---------------- phase B finisher ----------------
        if (tid < 128) {
            float v = 0.f;
#pragma unroll
            for (int k8 = 0; k8 < 8; ++k8)
                v += redA[k8 * 128 + frw * 32 + fb];
            float o = sigm(po_lds[frw * 32 + fb] + v);
            float hy = o * tanh_fast(cy_lds[frw * 32 + fb]);
            agent_store(&out[(size_t)t * HS + (size_t)fb * H_DIM + fr], hy);
        }
        __syncthreads();

        // ---------------- barrier: h(t) globally visible ----------------
        if (tid == 0) arrive_wait(grp_ctr, master, grpid, bidx);
        bidx++;
        __builtin_amdgcn_fence(__ATOMIC_ACQUIRE, "workgroup");
        __syncthreads();
    }
}

// ---------------------------------------------------------------------------
extern "C" void kernel_launch(void* const* d_in, const int* in_sizes, int n_in,
                              void* d_out, int out_size, void* d_ws, size_t ws_size,
                              hipStream_t stream) {
    const float* X     = (const float*)d_in[0];
    const float* h0    = (const float*)d_in[1];
    const float* c0    = (const float*)d_in[2];
    const float* w_ii  = (const float*)d_in[3];
    const float* w_hi  = (const float*)d_in[4];
    const float* w_ci  = (const float*)d_in[5];
    const float* w_if  = (const float*)d_in[6];
    const float* w_hf  = (const float*)d_in[7];
    const float* w_cf  = (const float*)d_in[8];
    const float* w_ic  = (const float*)d_in[9];
    const float* w_hc  = (const float*)d_in[10];
    const float* w_io  = (const float*)d_in[11];
    const float* w_ho  = (const float*)d_in[12];
    const float* w_cyo = (const float*)d_in[13];
    const float* b_ii  = (const float*)d_in[14];
    const float* b_hi  = (const float*)d_in[15];
    const float* b_ci  = (const float*)d_in[16];
    const float* b_if  = (const float*)d_in[17];
    const float* b_hf  = (const float*)d_in[18];
    const float* b_cf  = (const float*)d_in[19];
    const float* b_ic  = (const float*)d_in[20];
    const float* b_hc  = (const float*)d_in[21];
    const float* b_io  = (const float*)d_in[22];
    const float* b_ho  = (const float*)d_in[23];
    const float* b_cyo = (const float*)d_in[24];
    float* out = (float*)d_out;

    // ws carve: G (Tc*131072 f) | bias4 (4096 f) | c_hist ((Tc+1)*HS f) | counters
    int Tc = 512;
    while (Tc > 8) {
        size_t need = ((size_t)Tc * 131072 + 4096 + (size_t)(Tc + 1) * HS) * 4 + 2048;
        if (need <= ws_size) break;
        Tc >>= 1;
    }

    float* G      = (float*)d_ws;
    float* bias4  = G + (size_t)Tc * 131072;
    float* c_hist = bias4 + 4096;
    unsigned* grp_ctr = (unsigned*)(c_hist + (size_t)(Tc + 1) * HS);
    unsigned* master  = grp_ctr + 256;   // own cache line region

    bias_combine<<<4, 256, 0, stream>>>(b_ii, b_hi, b_ci, b_if, b_hf, b_cf,
                                        b_ic, b_hc, b_io, b_ho, b_cyo, bias4);

    const float* c_init = c0;
    for (int t0 = 0; t0 < T_LEN; t0 += Tc) {
        pregemm<<<dim3(Tc * 32 / BM, 4096 / BN), 256, 0, stream>>>(
            X + (size_t)t0 * B_SZ * I_DIM, w_ii, w_if, w_ic, w_io, bias4, G);
        hipMemsetAsync(grp_ctr, 0, 2048, stream);

        const float* Gp = G;
        float* chp = c_hist;
        unsigned* gcp = grp_ctr;
        unsigned* mp = master;
        int t0v = t0, Tcv = Tc;
        void* args[] = {
            (void*)&Gp, (void*)&h0, (void*)&c_init,
            (void*)&w_hi, (void*)&w_ci, (void*)&w_hf, (void*)&w_cf,
            (void*)&w_hc, (void*)&w_ho, (void*)&w_cyo,
            (void*)&out, (void*)&chp, (void*)&gcp, (void*)&mp,
            (void*)&t0v, (void*)&Tcv
        };
        hipLaunchCooperativeKernel((const void*)lstm_scan, dim3(NBLK), dim3(512),
                                   args, 0, stream);
        c_init = c_hist + (size_t)Tc * HS;   // kernel boundary gives coherence
    }
}

// Round 5
// 15730.191 us; speedup vs baseline: 6.6752x; 1.8947x over previous
//
#include <hip/hip_runtime.h>
#include <math.h>

#define T_LEN 512
#define B_SZ  32
#define I_DIM 512
#define H_DIM 1024
#define NBLK  256
#define HS    (B_SZ * H_DIM)   // 32768 floats per state snapshot

typedef float fx4 __attribute__((ext_vector_type(4)));   // nontemporal-compatible

// ---------------------------------------------------------------------------
// bias_combine
// ---------------------------------------------------------------------------
__global__ void bias_combine(const float* __restrict__ b_ii, const float* __restrict__ b_hi,
                             const float* __restrict__ b_ci, const float* __restrict__ b_if,
                             const float* __restrict__ b_hf, const float* __restrict__ b_cf,
                             const float* __restrict__ b_ic, const float* __restrict__ b_hc,
                             const float* __restrict__ b_io, const float* __restrict__ b_ho,
                             const float* __restrict__ b_cyo, float* __restrict__ bias4) {
    int r = blockIdx.x * 256 + threadIdx.x;
    if (r < H_DIM) {
        bias4[r]        = b_ii[r] + b_hi[r] + b_ci[r];
        bias4[1024 + r] = b_if[r] + b_hf[r] + b_cf[r];
        bias4[2048 + r] = b_ic[r] + b_hc[r];
        bias4[3072 + r] = b_io[r] + b_ho[r] + b_cyo[r];
    }
}

// ---------------------------------------------------------------------------
// pregemm: C[n][m] = sum_k A[m][k]*W[nloc][k] + bias4[n]   (TRANSPOSED output:
// leading dim M, so the scan's per-step reads are coalesced over m.)
// M = Tc*32, K = 512, N = 4096. 128x128 tile, BK=16, 256 thr, 8x8/thread.
// ---------------------------------------------------------------------------
#define BM 128
#define BN 128
#define BK 16
__global__ __launch_bounds__(256) void pregemm(const float* __restrict__ A,
                                               const float* __restrict__ w0,
                                               const float* __restrict__ w1,
                                               const float* __restrict__ w2,
                                               const float* __restrict__ w3,
                                               const float* __restrict__ bias4,
                                               float* __restrict__ C, int M) {
    __shared__ float As[BK][BM + 4];
    __shared__ float Bs[BK][BN + 4];
    int tid = threadIdx.x;
    int n0 = blockIdx.y * BN;
    const float* W = (n0 < 1024) ? w0 : (n0 < 2048) ? w1 : (n0 < 3072) ? w2 : w3;
    int nloc = n0 & 1023;

    int lr = tid >> 2;
    int lk = (tid & 3) << 2;
    const float* Arow = A + (size_t)(blockIdx.x * BM + lr) * I_DIM + lk;
    const float* Brow = W + (size_t)(nloc + lr) * I_DIM + lk;

    float acc[8][8];
#pragma unroll
    for (int i = 0; i < 8; ++i)
#pragma unroll
        for (int j = 0; j < 8; ++j) acc[i][j] = 0.f;

    int mth = (tid >> 4) << 3;
    int nth = (tid & 15) << 3;

    for (int kt = 0; kt < I_DIM; kt += BK) {
        float4 a0 = *(const float4*)(Arow + kt);
        float4 a1 = *(const float4*)(Arow + 64 * I_DIM + kt);
        float4 b0 = *(const float4*)(Brow + kt);
        float4 b1 = *(const float4*)(Brow + 64 * I_DIM + kt);
        __syncthreads();
        As[lk + 0][lr] = a0.x; As[lk + 1][lr] = a0.y; As[lk + 2][lr] = a0.z; As[lk + 3][lr] = a0.w;
        As[lk + 0][lr + 64] = a1.x; As[lk + 1][lr + 64] = a1.y; As[lk + 2][lr + 64] = a1.z; As[lk + 3][lr + 64] = a1.w;
        Bs[lk + 0][lr] = b0.x; Bs[lk + 1][lr] = b0.y; Bs[lk + 2][lr] = b0.z; Bs[lk + 3][lr] = b0.w;
        Bs[lk + 0][lr + 64] = b1.x; Bs[lk + 1][lr + 64] = b1.y; Bs[lk + 2][lr + 64] = b1.z; Bs[lk + 3][lr + 64] = b1.w;
        __syncthreads();
#pragma unroll
        for (int j = 0; j < BK; ++j) {
            float am[8], bn[8];
            *(float4*)&am[0] = *(const float4*)&As[j][mth];
            *(float4*)&am[4] = *(const float4*)&As[j][mth + 4];
            *(float4*)&bn[0] = *(const float4*)&Bs[j][nth];
            *(float4*)&bn[4] = *(const float4*)&Bs[j][nth + 4];
#pragma unroll
            for (int ii = 0; ii < 8; ++ii)
#pragma unroll
                for (int jj = 0; jj < 8; ++jj) acc[ii][jj] += am[ii] * bn[jj];
        }
    }

    int mbase = blockIdx.x * BM + mth;
#pragma unroll
    for (int jj = 0; jj < 8; ++jj) {
        int n = n0 + nth + jj;
        float bn = bias4[n];
        float* crow = C + (size_t)n * M + mbase;
        fx4 v0, v1;
        v0.x = acc[0][jj] + bn; v0.y = acc[1][jj] + bn;
        v0.z = acc[2][jj] + bn; v0.w = acc[3][jj] + bn;
        v1.x = acc[4][jj] + bn; v1.y = acc[5][jj] + bn;
        v1.z = acc[6][jj] + bn; v1.w = acc[7][jj] + bn;
        __builtin_nontemporal_store(v0, (fx4*)crow);
        __builtin_nontemporal_store(v1, (fx4*)(crow + 4));
    }
}

// ---------------------------------------------------------------------------
// helpers
// ---------------------------------------------------------------------------
__device__ __forceinline__ float sigm(float x) { return 1.f / (1.f + __expf(-x)); }
__device__ __forceinline__ float tanh_fast(float x) { return 2.f / (1.f + __expf(-2.f * x)) - 1.f; }

__device__ __forceinline__ void agent_store(float* p, float v) {
    __hip_atomic_store(p, v, __ATOMIC_RELAXED, __HIP_MEMORY_SCOPE_AGENT);
}

// two-level arrival barrier (thread 0 only); no cache-flush fences.
__device__ __forceinline__ void arrive_wait(unsigned* grp, unsigned* master,
                                            int grpid, unsigned bidx) {
    unsigned old = __hip_atomic_fetch_add(&grp[grpid * 16], 1u,
                                          __ATOMIC_RELAXED, __HIP_MEMORY_SCOPE_AGENT);
    if (old == bidx * 32u + 31u)
        __hip_atomic_fetch_add(master, 1u, __ATOMIC_RELAXED, __HIP_MEMORY_SCOPE_AGENT);
    while (__hip_atomic_load(master, __ATOMIC_RELAXED, __HIP_MEMORY_SCOPE_AGENT)
           < (bidx + 1u) * 8u)
        __builtin_amdgcn_s_sleep(1);
}

// ---------------------------------------------------------------------------
// Persistent cooperative scan. 256 blocks x 512 thr (8 waves); block owns
// rows r0..r0+3. ALL weights for those rows (112 KB) live in LDS, loaded once.
// Wave wv owns k-slice [wv*128, wv*128+128). Lane: half = gate-row group,
// b = batch. Weight LDS reads broadcast across the 32 b-lanes (2-way across
// halves = free). State (h/c/cy) read directly from global (L1/L2 resident).
// Cross-wave k-reduction via LDS; finisher (128 thr) applies gates.
// G layout is [gate-row][m] (m = tt*32 + b) -> coalesced finisher reads.
// ---------------------------------------------------------------------------
#define SMEM_FLOATS (24576 + 4096 + 6144 + 128 + 128)
#define SMEM_BYTES  (SMEM_FLOATS * 4)

__global__ __launch_bounds__(512) void lstm_scan(
    const float* __restrict__ G,
    const float* __restrict__ h0,
    const float* __restrict__ c_init,
    const float* __restrict__ w_hi, const float* __restrict__ w_ci,
    const float* __restrict__ w_hf, const float* __restrict__ w_cf,
    const float* __restrict__ w_hc, const float* __restrict__ w_ho,
    const float* __restrict__ w_cyo,
    float* __restrict__ out,
    float* __restrict__ c_hist,
    unsigned* __restrict__ grp_ctr,
    unsigned* __restrict__ master,
    int t0, int Tc, int M)
{
    extern __shared__ float smem[];
    float* wA     = smem;             // [6][4][1024]  96 KB
    float* wB     = wA + 24576;       // [4][1024]     16 KB
    float* redA   = wB + 4096;        // [8][24][32]   24 KB
    float* po_lds = redA + 6144;      // [4][32]
    float* cy_lds = po_lds + 128;     // [4][32]

    int tid = threadIdx.x;
    int blk = blockIdx.x;
    int r0 = blk * 4;
    int grpid = blk & 7;

    int wv = tid >> 6;            // 0..7 : k-split
    int lane = tid & 63;
    int half = lane >> 5;         // gate-row group
    int b = lane & 31;            // batch
    int kbase = wv * 128;

    // ---- load weight slices into LDS once ----
    {
        const float* srcs[7] = {w_hi, w_ci, w_hf, w_cf, w_hc, w_ho, w_cyo};
#pragma unroll
        for (int m = 0; m < 7; ++m) {
            const float4* s = (const float4*)(srcs[m] + (size_t)r0 * H_DIM);
            float4* d = (float4*)(m < 6 ? (wA + m * 4096) : wB);
            d[tid] = s[tid];
            d[tid + 512] = s[tid + 512];
        }
    }
    __syncthreads();

    // slot gates: slot0/2 consume h, slot1 consumes c — uniform across halves.
    int gs0 = half ? 2 : 0;       // w_hf : w_hi   (h)
    int gs1 = half ? 3 : 1;       // w_cf : w_ci   (c)
    int gs2 = half ? 5 : 4;       // w_ho : w_hc   (h)

    // LDS weight pointers (kbase folded in, step-invariant)
    const float* wpk[12];
#pragma unroll
    for (int q = 0; q < 4; ++q) {
        wpk[q]     = wA + (gs0 * 4 + q) * 1024 + kbase;
        wpk[4 + q] = wA + (gs1 * 4 + q) * 1024 + kbase;
        wpk[8 + q] = wA + (gs2 * 4 + q) * 1024 + kbase;
    }
    const float* wBk0 = wB + (half * 2 + 0) * 1024 + kbase;
    const float* wBk1 = wB + (half * 2 + 1) * 1024 + kbase;

    // finisher mapping (threads 0..127)
    int frw = (tid >> 5) & 3;
    int fb = tid & 31;
    int fr = r0 + frw;

    unsigned bidx = 0;

    for (int tt = 0; tt < Tc; ++tt) {
        int t = t0 + tt;
        const float* hp = (t == 0) ? h0 : out + (size_t)(t - 1) * HS;
        const float* cp = (tt == 0) ? c_init : c_hist + (size_t)tt * HS;
        float* cw = c_hist + (size_t)(tt + 1) * HS;

        // ---------------- phase A main: 24 gate-row partial dots ----------------
        const float* hb = hp + (size_t)b * H_DIM + kbase;
        const float* cb = cp + (size_t)b * H_DIM + kbase;
        float acc[12];
#pragma unroll
        for (int j = 0; j < 12; ++j) acc[j] = 0.f;

#pragma unroll 4
        for (int it = 0; it < 32; ++it) {
            int k = it * 4;
            float4 h4 = *(const float4*)(hb + k);
            float4 c4 = *(const float4*)(cb + k);
#pragma unroll
            for (int q = 0; q < 4; ++q) {
                float4 w4 = *(const float4*)(wpk[q] + k);
                acc[q] += w4.x * h4.x + w4.y * h4.y + w4.z * h4.z + w4.w * h4.w;
            }
#pragma unroll
            for (int q = 0; q < 4; ++q) {
                float4 w4 = *(const float4*)(wpk[4 + q] + k);
                acc[4 + q] += w4.x * c4.x + w4.y * c4.y + w4.z * c4.z + w4.w * c4.w;
            }
#pragma unroll
            for (int q = 0; q < 4; ++q) {
                float4 w4 = *(const float4*)(wpk[8 + q] + k);
                acc[8 + q] += w4.x * h4.x + w4.y * h4.y + w4.z * h4.z + w4.w * h4.w;
            }
        }
#pragma unroll
        for (int q = 0; q < 4; ++q) {
            redA[wv * 768 + (gs0 * 4 + q) * 32 + b] = acc[q];
            redA[wv * 768 + (gs1 * 4 + q) * 32 + b] = acc[4 + q];
            redA[wv * 768 + (gs2 * 4 + q) * 32 + b] = acc[8 + q];
        }
        __syncthreads();

        // ---------------- phase A finisher (threads 0..127) ----------------
        if (tid < 128) {
            float s[6];
#pragma unroll
            for (int g = 0; g < 6; ++g) {
                float v = 0.f;
#pragma unroll
                for (int k8 = 0; k8 < 8; ++k8)
                    v += redA[k8 * 768 + (g * 4 + frw) * 32 + fb];
                s[g] = v;
            }
            int m = tt * 32 + fb;
            float xi = __builtin_nontemporal_load(G + (size_t)(0 * 1024 + fr) * M + m);
            float xf = __builtin_nontemporal_load(G + (size_t)(1 * 1024 + fr) * M + m);
            float xg = __builtin_nontemporal_load(G + (size_t)(2 * 1024 + fr) * M + m);
            float xo = __builtin_nontemporal_load(G + (size_t)(3 * 1024 + fr) * M + m);
            float iv = sigm(xi + s[0] + s[1]);
            float fv = sigm(xf + s[2] + s[3]);
            float gv = tanh_fast(xg + s[4]);
            float cold = cp[(size_t)fb * H_DIM + fr];
            float cy = fv * cold + iv * gv;
            agent_store(&cw[(size_t)fb * H_DIM + fr], cy);
            po_lds[frw * 32 + fb] = xo + s[5];
            cy_lds[frw * 32 + fb] = cy;
        }
        __syncthreads();              // drains the agent stores too

        // ---------------- barrier: cy globally visible ----------------
        if (tid == 0) arrive_wait(grp_ctr, master, grpid, bidx);
        bidx++;
        __builtin_amdgcn_fence(__ATOMIC_ACQUIRE, "workgroup");
        __syncthreads();

        // ---------------- phase B main: o-gate peephole dot ----------------
        const float* cyb = cw + (size_t)b * H_DIM + kbase;
        float a0 = 0.f, a1 = 0.f;
#pragma unroll 4
        for (int it = 0; it < 32; ++it) {
            int k = it * 4;
            float4 cy4 = *(const float4*)(cyb + k);
            float4 w0 = *(const float4*)(wBk0 + k);
            float4 w1 = *(const float4*)(wBk1 + k);
            a0 += w0.x * cy4.x + w0.y * cy4.y + w0.z * cy4.z + w0.w * cy4.w;
            a1 += w1.x * cy4.x + w1.y * cy4.y + w1.z * cy4.z + w1.w * cy4.w;
        }
        redA[wv * 128 + (half * 2 + 0) * 32 + b] = a0;
        redA[wv * 128 + (half * 2 + 1) * 32 + b] = a1;
        __syncthreads();

        // ---------------- phase B finisher ----------------
        if (tid < 128) {
            float v = 0.f;
#pragma unroll
            for (int k8 = 0; k8 < 8; ++k8)
                v += redA[k8 * 128 + frw * 32 + fb];
            float o = sigm(po_lds[frw * 32 + fb] + v);
            float hy = o * tanh_fast(cy_lds[frw * 32 + fb]);
            agent_store(&out[(size_t)t * HS + (size_t)fb * H_DIM + fr], hy);
        }
        __syncthreads();

        // ---------------- barrier: h(t) globally visible ----------------
        if (tid == 0) arrive_wait(grp_ctr, master, grpid, bidx);
        bidx++;
        __builtin_amdgcn_fence(__ATOMIC_ACQUIRE, "workgroup");
        __syncthreads();
    }
}

// ---------------------------------------------------------------------------
extern "C" void kernel_launch(void* const* d_in, const int* in_sizes, int n_in,
                              void* d_out, int out_size, void* d_ws, size_t ws_size,
                              hipStream_t stream) {
    const float* X     = (const float*)d_in[0];
    const float* h0    = (const float*)d_in[1];
    const float* c0    = (const float*)d_in[2];
    const float* w_ii  = (const float*)d_in[3];
    const float* w_hi  = (const float*)d_in[4];
    const float* w_ci  = (const float*)d_in[5];
    const float* w_if  = (const float*)d_in[6];
    const float* w_hf  = (const float*)d_in[7];
    const float* w_cf  = (const float*)d_in[8];
    const float* w_ic  = (const float*)d_in[9];
    const float* w_hc  = (const float*)d_in[10];
    const float* w_io  = (const float*)d_in[11];
    const float* w_ho  = (const float*)d_in[12];
    const float* w_cyo = (const float*)d_in[13];
    const float* b_ii  = (const float*)d_in[14];
    const float* b_hi  = (const float*)d_in[15];
    const float* b_ci  = (const float*)d_in[16];
    const float* b_if  = (const float*)d_in[17];
    const float* b_hf  = (const float*)d_in[18];
    const float* b_cf  = (const float*)d_in[19];
    const float* b_ic  = (const float*)d_in[20];
    const float* b_hc  = (const float*)d_in[21];
    const float* b_io  = (const float*)d_in[22];
    const float* b_ho  = (const float*)d_in[23];
    const float* b_cyo = (const float*)d_in[24];
    float* out = (float*)d_out;

    (void)hipFuncSetAttribute((const void*)lstm_scan,
                              hipFuncAttributeMaxDynamicSharedMemorySize, SMEM_BYTES);

    // ws carve: G (4096 x M floats) | bias4 | c_hist ((Tc+1)*HS) | counters
    int Tc = 512;
    while (Tc > 8) {
        size_t need = ((size_t)Tc * 131072 + 4096 + (size_t)(Tc + 1) * HS) * 4 + 2048;
        if (need <= ws_size) break;
        Tc >>= 1;
    }
    int M = Tc * 32;

    float* G      = (float*)d_ws;
    float* bias4  = G + (size_t)Tc * 131072;
    float* c_hist = bias4 + 4096;
    unsigned* grp_ctr = (unsigned*)(c_hist + (size_t)(Tc + 1) * HS);
    unsigned* master  = grp_ctr + 256;

    bias_combine<<<4, 256, 0, stream>>>(b_ii, b_hi, b_ci, b_if, b_hf, b_cf,
                                        b_ic, b_hc, b_io, b_ho, b_cyo, bias4);

    const float* c_init = c0;
    for (int t0 = 0; t0 < T_LEN; t0 += Tc) {
        pregemm<<<dim3(M / BM, 4096 / BN), 256, 0, stream>>>(
            X + (size_t)t0 * B_SZ * I_DIM, w_ii, w_if, w_ic, w_io, bias4, G, M);
        (void)hipMemsetAsync(grp_ctr, 0, 2048, stream);

        const float* Gp = G;
        float* chp = c_hist;
        unsigned* gcp = grp_ctr;
        unsigned* mp = master;
        int t0v = t0, Tcv = Tc, Mv = M;
        void* args[] = {
            (void*)&Gp, (void*)&h0, (void*)&c_init,
            (void*)&w_hi, (void*)&w_ci, (void*)&w_hf, (void*)&w_cf,
            (void*)&w_hc, (void*)&w_ho, (void*)&w_cyo,
            (void*)&out, (void*)&chp, (void*)&gcp, (void*)&mp,
            (void*)&t0v, (void*)&Tcv, (void*)&Mv
        };
        (void)hipLaunchCooperativeKernel((const void*)lstm_scan, dim3(NBLK), dim3(512),
                                         args, SMEM_BYTES, stream);
        c_init = c_hist + (size_t)Tc * HS;
    }
}